// Round 4
// baseline (412.159 us; speedup 1.0000x reference)
//
#include <hip/hip_runtime.h>
#include <hip/hip_bf16.h>
#include <stdint.h>

// Problem constants: N=8, CIN=512, COUT=512, K=3, H=W=64
// out = demod[n,co]*sqrt2 * conv(cw, s[n,ci]*x) + nw*noise + bias, leaky(0.2)

typedef __attribute__((ext_vector_type(8))) short short8;
typedef __attribute__((ext_vector_type(4))) float f32x4;
typedef __attribute__((ext_vector_type(4))) unsigned int uint4v;

__device__ __forceinline__ unsigned short f2bf(float f) {
  unsigned u = __builtin_bit_cast(unsigned, f);
  u += 0x7FFFu + ((u >> 16) & 1u);   // round-to-nearest-even
  return (unsigned short)(u >> 16);
}

__device__ __forceinline__ void g2l16(const void* g, void* l) {
  __builtin_amdgcn_global_load_lds(
      (const __attribute__((address_space(1))) void*)g,
      (__attribute__((address_space(3))) void*)l, 16, 0, 0);
}

// ---------------- k_wprep: s-GEMV (0..7) | Wt (8..135) | wsq (136..263) ----------
// All roles independent (no cross-block deps). ~264 small blocks.
// Wt layout: [cb 8][kb 16]{ [tap 9][mt 4][lhi 4][m 16][8] } bf16, tile 36864 B.
__global__ void k_wprep(const float* __restrict__ style, const float* __restrict__ mw,
                        const float* __restrict__ mb, const float* __restrict__ cw,
                        float* __restrict__ s_g, float* __restrict__ wsq,
                        unsigned short* __restrict__ Wt) {
  __shared__ __align__(16) char smem[74240];
  int t = threadIdx.x;
  int b = blockIdx.x;
  if (b < 8) {
    // ---- s[n,:] GEMV: lanes along k (coalesced), 16-lane groups ----
    int n = b;
    float* stl = (float*)smem;   // style[n,:] 2048 B
    stl[t] = style[n * 512 + t];
    stl[t + 256] = style[n * 512 + 256 + t];
    __syncthreads();
    int lane = t & 63, wv = t >> 6;
    int g = lane >> 4, l = lane & 15;
#pragma unroll 2
    for (int cr = 0; cr < 32; ++cr) {
      int ci = wv * 128 + cr * 4 + g;
      const float* mr = mw + (size_t)ci * 512;
      float sum = 0.f;
#pragma unroll
      for (int it = 0; it < 8; ++it) {
        f32x4 a = *(const f32x4*)(mr + l * 4 + it * 64);
        f32x4 sv = *(const f32x4*)(stl + l * 4 + it * 64);
        sum += a.x * sv.x + a.y * sv.y + a.z * sv.z + a.w * sv.w;
      }
      sum += __shfl_xor(sum, 1, 64);
      sum += __shfl_xor(sum, 2, 64);
      sum += __shfl_xor(sum, 4, 64);
      sum += __shfl_xor(sum, 8, 64);
      if (l == 0) s_g[n * 512 + ci] = sum + mb[ci];
    }
  } else if (b < 136) {
    // ---- Wt build: one block per (cb,kb); LDS stride 289 -> conflict-free ----
    int bb = b - 8;
    int cb = bb >> 4, kb = bb & 15;
    float* ldsf = (float*)smem;   // [64][289]  73984 B
#pragma unroll
    for (int i = 0; i < 72; ++i) {
      int idx = t + i * 256;
      int seg = idx / 288, off = idx - seg * 288;
      ldsf[seg * 289 + off] = cw[(size_t)(cb * 64 + seg) * 4608 + kb * 288 + off];
    }
    __syncthreads();
    unsigned short* ob = Wt + (size_t)(cb * 16 + kb) * 18432;
#pragma unroll
    for (int i = 0; i < 9; ++i) {
      int c = t + i * 256;   // chunk 0..2303
      int m = c & 15, lhi = (c >> 4) & 3, mt = (c >> 6) & 3, tap = c >> 8;
      int co_rel = mt * 16 + m;
      unsigned v[8];
#pragma unroll
      for (int j = 0; j < 8; ++j)
        v[j] = f2bf(ldsf[co_rel * 289 + (lhi * 8 + j) * 9 + tap]);
      uint4v o;
      o.x = v[0] | (v[1] << 16);
      o.y = v[2] | (v[3] << 16);
      o.z = v[4] | (v[5] << 16);
      o.w = v[6] | (v[7] << 16);
      *(uint4v*)(ob + (size_t)c * 8) = o;
    }
  } else {
    // ---- wsq[co,ci] = sum_tap cw^2 : 262144 entries, 2048/block ----
    int base = (b - 136) * 2048;
#pragma unroll
    for (int u = 0; u < 8; ++u) {
      int id = base + u * 256 + t;
      const float* p = cw + (size_t)id * 9;
      float a = 0.f;
#pragma unroll
      for (int j = 0; j < 9; ++j) a += p[j] * p[j];
      wsq[id] = a;
    }
  }
}

// ---------------- k_conv: implicit-GEMM conv with DIRECT x staging ---------------
// No Xp intermediate: per kb-step, stage [10 row][32 ci][66 col] modulated bf16
// into lds_x ([row][lhi 4][col 66][8ci], row stride 2112 shorts - byte-identical
// layout to the verified MFMA read path). Halo = masked zeros. demod computed in
// prologue from s_g + wsq. Scalar f32 x-loads: 16 lanes/row -> full 64B lines;
// 8 cb-blocks (same XCD by grid linearization mod 8) share each x-tile in L2.
__global__ void __launch_bounds__(256, 2) k_conv(
    const unsigned short* __restrict__ Wt, const float* __restrict__ x,
    const float* __restrict__ s_g, const float* __restrict__ wsq,
    const float* __restrict__ noise, const float* __restrict__ nw_p,
    const float* __restrict__ act_bias, float* __restrict__ out) {
  __shared__ __align__(16) char smem[81408];
  short* lds_a = (short*)smem;             // 36864 B
  short* lds_x = (short*)(smem + 36864);   // 42240 B (end 79104)
  float* sxf   = (float*)(smem + 79104);   // s[n,0..511]  2048 B
  float* demf  = (float*)(smem + 81152);   // demod[64]     256 B
  int t = threadIdx.x;
  int r0 = blockIdx.x * 8;
  int cb = blockIdx.y;
  int n = blockIdx.z;
  int lane = t & 63, wv = t >> 6;
  int l15 = lane & 15, lhi4 = lane >> 4;

  // ---- prologue: s -> LDS, then demod for this block's 64 co ----
  sxf[t] = s_g[n * 512 + t];
  sxf[t + 256] = s_g[n * 512 + 256 + t];
  __syncthreads();
  {
    int g = t >> 5, l5 = t & 31;
    const float* wb = wsq + (size_t)(cb * 64) * 512;
#pragma unroll
    for (int q = 0; q < 8; ++q) {
      int coi = g * 8 + q;
      float sum = 0.f;
#pragma unroll
      for (int i = 0; i < 4; ++i) {
        int c4 = l5 * 4 + i * 128;
        f32x4 w4 = *(const f32x4*)(wb + (size_t)coi * 512 + c4);
        f32x4 s4 = *(const f32x4*)(sxf + c4);
        sum += s4.x * s4.x * w4.x + s4.y * s4.y * w4.y +
               s4.z * s4.z * w4.z + s4.w * s4.w * w4.w;
      }
      sum += __shfl_xor(sum, 1, 64);
      sum += __shfl_xor(sum, 2, 64);
      sum += __shfl_xor(sum, 4, 64);
      sum += __shfl_xor(sum, 8, 64);
      sum += __shfl_xor(sum, 16, 64);
      if (l5 == 0) demf[coi] = rsqrtf(sum + 1e-8f) * 1.41421356237309515f;
    }
  }

  f32x4 acc[4][8];
#pragma unroll
  for (int a = 0; a < 4; ++a)
#pragma unroll
    for (int bq = 0; bq < 8; ++bq) acc[a][bq] = (f32x4){0.f, 0.f, 0.f, 0.f};

  const int aoff = lhi4 * 128 + l15 * 8;
  const int xoffb = lhi4 * 528 + (wv * 16 + l15) * 8;
  const unsigned short* abase = Wt + (size_t)cb * 16 * 18432;
  const float* xn = x + (size_t)n * 512 * 4096;

  for (int kb = 0; kb < 16; ++kb) {
    __syncthreads();
    // A: async global->LDS (unchanged, verified)
    const char* ab = (const char*)(abase + (size_t)kb * 18432);
#pragma unroll
    for (int i = 0; i < 9; ++i)
      g2l16(ab + i * 4096 + t * 16, (char*)lds_a + i * 4096 + t * 16);

    // X: direct staging. Passes 0..9: row=p, lhi=wv, col=lane (0..63).
    {
      int ci0 = kb * 32 + wv * 8;
      f32x4 sA = *(const f32x4*)(sxf + ci0);
      f32x4 sB = *(const f32x4*)(sxf + ci0 + 4);
      float cm = (lane >= 1) ? 1.f : 0.f;     // col 0 is left halo
      int xcc = lane - 1; if (xcc < 0) xcc = 0;
#pragma unroll
      for (int p = 0; p < 10; ++p) {
        int off = p * 2112 + wv * 528 + lane * 8;   // shorts
        int xr = r0 + p - 1;
        if ((unsigned)xr < 64u) {
          const float* bp = xn + (size_t)ci0 * 4096 + xr * 64 + xcc;
          float v0 = bp[0], v1 = bp[4096], v2 = bp[8192], v3 = bp[12288];
          float v4 = bp[16384], v5 = bp[20480], v6 = bp[24576], v7 = bp[28672];
          uint4v o;
          o.x = f2bf(v0 * sA.x * cm) | ((unsigned)f2bf(v1 * sA.y * cm) << 16);
          o.y = f2bf(v2 * sA.z * cm) | ((unsigned)f2bf(v3 * sA.w * cm) << 16);
          o.z = f2bf(v4 * sB.x * cm) | ((unsigned)f2bf(v5 * sB.y * cm) << 16);
          o.w = f2bf(v6 * sB.z * cm) | ((unsigned)f2bf(v7 * sB.w * cm) << 16);
          *(uint4v*)(lds_x + off) = o;
        } else {
          *(uint4v*)(lds_x + off) = (uint4v){0u, 0u, 0u, 0u};
        }
      }
      // Pass 10: cols 64 (img col 63) and 65 (right halo) for all 40 (row,lhi).
      if (t < 80) {
        int row = t >> 3, lhi = (t >> 1) & 3, c_lds = 64 + (t & 1);
        int off = row * 2112 + lhi * 528 + c_lds * 8;
        int xr = r0 + row - 1;
        if ((unsigned)xr < 64u && c_lds == 64) {
          int ci0b = kb * 32 + lhi * 8;
          f32x4 sC = *(const f32x4*)(sxf + ci0b);
          f32x4 sD = *(const f32x4*)(sxf + ci0b + 4);
          const float* bp = xn + (size_t)ci0b * 4096 + xr * 64 + 63;
          float v0 = bp[0], v1 = bp[4096], v2 = bp[8192], v3 = bp[12288];
          float v4 = bp[16384], v5 = bp[20480], v6 = bp[24576], v7 = bp[28672];
          uint4v o;
          o.x = f2bf(v0 * sC.x) | ((unsigned)f2bf(v1 * sC.y) << 16);
          o.y = f2bf(v2 * sC.z) | ((unsigned)f2bf(v3 * sC.w) << 16);
          o.z = f2bf(v4 * sD.x) | ((unsigned)f2bf(v5 * sD.y) << 16);
          o.w = f2bf(v6 * sD.z) | ((unsigned)f2bf(v7 * sD.w) << 16);
          *(uint4v*)(lds_x + off) = o;
        } else {
          *(uint4v*)(lds_x + off) = (uint4v){0u, 0u, 0u, 0u};
        }
      }
    }
    __syncthreads();

    // MFMA inner loop: byte-identical to verified schedule
#pragma unroll
    for (int dw = 0; dw < 3; ++dw) {
      short8 bf[10];
#pragma unroll
      for (int rr = 0; rr < 10; ++rr)
        bf[rr] = *(const short8*)(lds_x + rr * 2112 + dw * 8 + xoffb);
#pragma unroll
      for (int dh = 0; dh < 3; ++dh) {
#pragma unroll
        for (int mt = 0; mt < 4; ++mt) {
          short8 af = *(const short8*)(lds_a + (dh * 3 + dw) * 2048 + mt * 512 + aoff);
#pragma unroll
          for (int ri = 0; ri < 8; ++ri)
            acc[mt][ri] =
                __builtin_amdgcn_mfma_f32_16x16x32_bf16(af, bf[ri + dh], acc[mt][ri], 0, 0, 0);
        }
      }
    }
  }

  float nw = nw_p[0];
  int col = wv * 16 + l15;
  float nz[8];
#pragma unroll
  for (int ri = 0; ri < 8; ++ri)
    nz[ri] = nw * noise[((size_t)n * 64 + r0 + ri) * 64 + col];
#pragma unroll
  for (int mt = 0; mt < 4; ++mt) {
    f32x4 dm4 = *(const f32x4*)(demf + mt * 16 + lhi4 * 4);
#pragma unroll
    for (int c = 0; c < 4; ++c) {
      int co = cb * 64 + mt * 16 + lhi4 * 4 + c;
      float ab2 = act_bias[co];
      float dm = dm4[c];
#pragma unroll
      for (int ri = 0; ri < 8; ++ri) {
        float v = dm * acc[mt][ri][c] + nz[ri] + ab2;
        v = v > 0.f ? v : 0.2f * v;
        out[(((size_t)n * 512 + co) * 64 + (r0 + ri)) * 64 + col] = v;
      }
    }
  }
}

extern "C" void kernel_launch(void* const* d_in, const int* in_sizes, int n_in,
                              void* d_out, int out_size, void* d_ws, size_t ws_size,
                              hipStream_t stream) {
  const float* x     = (const float*)d_in[0];
  const float* style = (const float*)d_in[1];
  const float* noise = (const float*)d_in[2];
  const float* cw    = (const float*)d_in[3];
  const float* mw    = (const float*)d_in[4];
  const float* mb    = (const float*)d_in[5];
  const float* nw    = (const float*)d_in[6];
  const float* ab    = (const float*)d_in[7];
  float* out = (float*)d_out;

  char* ws = (char*)d_ws;
  float* s_g  = (float*)ws;                              // 16 KB
  float* wsq  = (float*)(ws + 32768);                    // 1 MB
  unsigned short* Wt = (unsigned short*)(ws + 1081344);  // 4,718,592 B (end ~5.8 MB)

  k_wprep<<<264, 256, 0, stream>>>(style, mw, mb, cw, s_g, wsq, Wt);
  k_conv<<<dim3(8, 8, 8), 256, 0, stream>>>(Wt, x, s_g, wsq, noise, nw, ab, out);
}

// Round 5
// 295.367 us; speedup vs baseline: 1.3954x; 1.3954x over previous
//
#include <hip/hip_runtime.h>
#include <hip/hip_bf16.h>
#include <stdint.h>

// Problem constants: N=8, CIN=512, COUT=512, K=3, H=W=64
// out = demod[n,co]*sqrt2 * conv(cw, s[n,ci]*x) + nw*noise + bias, leaky(0.2)

typedef __attribute__((ext_vector_type(8))) short short8;
typedef __attribute__((ext_vector_type(4))) float f32x4;
typedef __attribute__((ext_vector_type(4))) unsigned int uint4v;
typedef __attribute__((ext_vector_type(2))) unsigned int uint2v;

__device__ __forceinline__ unsigned short f2bf(float f) {
  unsigned u = __builtin_bit_cast(unsigned, f);
  u += 0x7FFFu + ((u >> 16) & 1u);   // round-to-nearest-even
  return (unsigned short)(u >> 16);
}

__device__ __forceinline__ void g2l16(const void* g, void* l) {
  __builtin_amdgcn_global_load_lds(
      (const __attribute__((address_space(1))) void*)g,
      (__attribute__((address_space(3))) void*)l, 16, 0, 0);
}

// ---------------- k_prep: all precompute, <=37888 B LDS -> 4 blocks/CU ----------
// blocks 0..1023   : xpad half-blocks (n,h,half): coop s-GEMV for own 256 ci,
//                    modulate+pack, transpose-write to Xp (R3 xpad split in two)
// blocks 1024..1031: s-GEMV -> s_g (for k_conv's demod prologue)
// blocks 1032..1159: Wt build, chunked [16][289] x 4 passes (18.5 KB LDS)
// blocks 1160..1287: wsq
// blocks 1288..1423: Xp halo zero
// Xp layout: [n 8][row 66][kb 16][lhi 4][col 66][8] bf16.
// Wt layout: [cb 8][kb 16]{ [tap 9][mt 4][lhi 4][m 16][8] } bf16, tile 36864 B.
__global__ void __launch_bounds__(256, 4) k_prep(
    const float* __restrict__ style, const float* __restrict__ mw,
    const float* __restrict__ mb, const float* __restrict__ cw,
    const float* __restrict__ x, float* __restrict__ s_g,
    float* __restrict__ wsq, unsigned short* __restrict__ Xp,
    unsigned short* __restrict__ Wt) {
  __shared__ __align__(16) char smem[37888];
  int t = threadIdx.x;
  int b = blockIdx.x;
  if (b < 1024) {
    // ---- xpad half-block: n, h, half (256 ci) ----
    int n = b >> 7;
    int rest = b & 127;
    int h = rest >> 1, half = rest & 1;
    short* ldsx = (short*)smem;              // [256][68]  34816 B
    float* sxf  = (float*)(smem + 34816);    // s[n, half-slice]  1024 B
    float* stl  = (float*)(smem + 35840);    // style[n,:]        2048 B (end 37888)
    stl[t] = style[n * 512 + t];
    stl[t + 256] = style[n * 512 + 256 + t];
    __syncthreads();
    // coop s-GEMV: lanes along k (coalesced), 16-lane groups, 256 ci
    {
      int lane = t & 63, wv = t >> 6;
      int g = lane >> 4, l = lane & 15;
#pragma unroll 2
      for (int cr = 0; cr < 16; ++cr) {
        int cil = wv * 64 + cr * 4 + g;      // 0..255
        int ci = half * 256 + cil;
        const float* mr = mw + (size_t)ci * 512;
        float sum = 0.f;
#pragma unroll
        for (int it = 0; it < 8; ++it) {
          f32x4 a = *(const f32x4*)(mr + l * 4 + it * 64);
          f32x4 sv = *(const f32x4*)(stl + l * 4 + it * 64);
          sum += a.x * sv.x + a.y * sv.y + a.z * sv.z + a.w * sv.w;
        }
        sum += __shfl_xor(sum, 1, 64);
        sum += __shfl_xor(sum, 2, 64);
        sum += __shfl_xor(sum, 4, 64);
        sum += __shfl_xor(sum, 8, 64);
        if (l == 0) sxf[cil] = sum + mb[ci];
      }
    }
    __syncthreads();
    // modulate + bf16 pack into LDS tile
    const float* xb = x + ((size_t)(n * 512 + half * 256)) * 4096 + h * 64;
#pragma unroll
    for (int i = 0; i < 16; ++i) {
      int L = t + i * 256;
      int cil = L >> 4, q = L & 15;
      f32x4 v = *(const f32x4*)(xb + (size_t)cil * 4096 + q * 4);
      float sv = sxf[cil];
      uint2v o;
      o.x = f2bf(v.x * sv) | ((unsigned)f2bf(v.y * sv) << 16);
      o.y = f2bf(v.z * sv) | ((unsigned)f2bf(v.w * sv) << 16);
      *(uint2v*)(ldsx + cil * 68 + q * 4) = o;
    }
    __syncthreads();
    // transpose-pack to Xp
    unsigned short* nb = Xp + (size_t)n * 2230272 + (size_t)(h + 1) * 33792;
#pragma unroll
    for (int r = 0; r < 8; ++r) {
      int u = t + r * 256;
      int cigl = u >> 6, col = u & 63;       // cigl 0..31
      int cig = half * 32 + cigl;
      unsigned v[8];
#pragma unroll
      for (int j = 0; j < 8; ++j)
        v[j] = (unsigned short)ldsx[(cigl * 8 + j) * 68 + col];
      uint4v o;
      o.x = v[0] | (v[1] << 16);
      o.y = v[2] | (v[3] << 16);
      o.z = v[4] | (v[5] << 16);
      o.w = v[6] | (v[7] << 16);
      *(uint4v*)(nb + ((size_t)cig * 66 + col + 1) * 8) = o;
    }
  } else if (b < 1032) {
    // ---- s_g[n,:] GEMV (verified R4 pattern) ----
    int n = b - 1024;
    float* stl = (float*)smem;   // style[n,:] 2048 B
    stl[t] = style[n * 512 + t];
    stl[t + 256] = style[n * 512 + 256 + t];
    __syncthreads();
    int lane = t & 63, wv = t >> 6;
    int g = lane >> 4, l = lane & 15;
#pragma unroll 2
    for (int cr = 0; cr < 32; ++cr) {
      int ci = wv * 128 + cr * 4 + g;
      const float* mr = mw + (size_t)ci * 512;
      float sum = 0.f;
#pragma unroll
      for (int it = 0; it < 8; ++it) {
        f32x4 a = *(const f32x4*)(mr + l * 4 + it * 64);
        f32x4 sv = *(const f32x4*)(stl + l * 4 + it * 64);
        sum += a.x * sv.x + a.y * sv.y + a.z * sv.z + a.w * sv.w;
      }
      sum += __shfl_xor(sum, 1, 64);
      sum += __shfl_xor(sum, 2, 64);
      sum += __shfl_xor(sum, 4, 64);
      sum += __shfl_xor(sum, 8, 64);
      if (l == 0) s_g[n * 512 + ci] = sum + mb[ci];
    }
  } else if (b < 1160) {
    // ---- Wt build: block (cb,kb); 4 passes of [16][289] floats (18496 B) ----
    int bb = b - 1032;
    int cb = bb >> 4, kb = bb & 15;
    float* ldsf = (float*)smem;   // [16][289]
    unsigned short* ob = Wt + (size_t)(cb * 16 + kb) * 18432;
#pragma unroll
    for (int p = 0; p < 4; ++p) {   // p == mt == co_rel>>4
      __syncthreads();
#pragma unroll
      for (int i = 0; i < 18; ++i) {
        int idx = t + i * 256;   // 0..4607
        int segl = idx / 288, off = idx - segl * 288;
        ldsf[segl * 289 + off] =
            cw[(size_t)(cb * 64 + p * 16 + segl) * 4608 + kb * 288 + off];
      }
      __syncthreads();
#pragma unroll
      for (int i = 0; i < 3; ++i) {
        int e = t + i * 256;     // 0..575: [tap 9][lhi 4][m 16]
        if (e < 576) {
          int tap = e >> 6, lhi = (e >> 4) & 3, m = e & 15;
          int c = tap * 256 + p * 64 + lhi * 16 + m;
          unsigned v[8];
#pragma unroll
          for (int j = 0; j < 8; ++j)
            v[j] = f2bf(ldsf[m * 289 + (lhi * 8 + j) * 9 + tap]);
          uint4v o;
          o.x = v[0] | (v[1] << 16);
          o.y = v[2] | (v[3] << 16);
          o.z = v[4] | (v[5] << 16);
          o.w = v[6] | (v[7] << 16);
          *(uint4v*)(ob + (size_t)c * 8) = o;
        }
      }
    }
  } else if (b < 1288) {
    // ---- wsq[co,ci] = sum_tap cw^2 : 2048 per block ----
    int base = (b - 1160) * 2048;
#pragma unroll
    for (int u = 0; u < 8; ++u) {
      int id = base + u * 256 + t;
      const float* p = cw + (size_t)id * 9;
      float a = 0.f;
#pragma unroll
      for (int j = 0; j < 9; ++j) a += p[j] * p[j];
      wsq[id] = a;
    }
  } else {
    // ---- halo zero: 16640 16B-chunks per n; 17 parts x 1024 chunks ----
    int bb = b - 1288;
    int n = bb / 17, part = bb % 17;
    uint4v z = (uint4v){0u, 0u, 0u, 0u};
    unsigned short* base = Xp + (size_t)n * 2230272;
#pragma unroll
    for (int i = 0; i < 4; ++i) {
      int id = part * 1024 + i * 256 + t;
      if (id < 16640) {
        size_t off;
        if (id < 8448) {                 // rows 0 and 65, full rows
          int row = (id < 4224) ? 0 : 65;
          int c = id - ((id < 4224) ? 0 : 4224);
          off = (size_t)row * 33792 + (size_t)c * 8;
        } else {                         // cols 0 and 65, rows 1..64
          int id2 = id - 8448;
          int row = 1 + (id2 >> 7);
          int rem = id2 & 127;
          int klhi = rem >> 1;
          int col = (rem & 1) ? 65 : 0;
          off = (size_t)row * 33792 + ((size_t)klhi * 66 + col) * 8;
        }
        *(uint4v*)(base + off) = z;
      }
    }
  }
}

// ---------------- k_conv: verified R0 schedule + demod prologue ------------------
// Prologue computes demod for this block's 64 co (R4-verified code) using the
// lds_x region as scratch (free before the kb loop), parks per-thread demod in
// 16 VGPRs, then runs the byte-identical staging/MFMA/epilogue.
__global__ void __launch_bounds__(256, 2) k_conv(
    const unsigned short* __restrict__ Wt, const unsigned short* __restrict__ Xp,
    const float* __restrict__ s_g, const float* __restrict__ wsq,
    const float* __restrict__ noise, const float* __restrict__ nw_p,
    const float* __restrict__ act_bias, float* __restrict__ out) {
  __shared__ __align__(16) char smem[81920];
  short* lds_a = (short*)smem;             // 36864 B
  short* lds_x = (short*)(smem + 36864);   // 45056 B (42240 used + staging slack)
  int t = threadIdx.x;
  int r0 = blockIdx.x * 8;
  int cb = blockIdx.y;
  int n = blockIdx.z;
  int lane = t & 63, wv = t >> 6;
  int l15 = lane & 15, lhi4 = lane >> 4;

  // ---- prologue: demod in lds_x scratch, then into registers ----
  f32x4 dmreg[4];
  {
    float* sxf  = (float*)(smem + 36864);          // 2048 B
    float* demf = (float*)(smem + 36864 + 2048);   // 256 B
    sxf[t] = s_g[n * 512 + t];
    sxf[t + 256] = s_g[n * 512 + 256 + t];
    __syncthreads();
    int g = t >> 5, l5 = t & 31;
    const float* wb = wsq + (size_t)(cb * 64) * 512;
#pragma unroll
    for (int q = 0; q < 8; ++q) {
      int coi = g * 8 + q;
      float sum = 0.f;
#pragma unroll
      for (int i = 0; i < 4; ++i) {
        int c4 = l5 * 4 + i * 128;
        f32x4 w4 = *(const f32x4*)(wb + (size_t)coi * 512 + c4);
        f32x4 s4 = *(const f32x4*)(sxf + c4);
        sum += s4.x * s4.x * w4.x + s4.y * s4.y * w4.y +
               s4.z * s4.z * w4.z + s4.w * s4.w * w4.w;
      }
      sum += __shfl_xor(sum, 1, 64);
      sum += __shfl_xor(sum, 2, 64);
      sum += __shfl_xor(sum, 4, 64);
      sum += __shfl_xor(sum, 8, 64);
      sum += __shfl_xor(sum, 16, 64);
      if (l5 == 0) demf[coi] = rsqrtf(sum + 1e-8f) * 1.41421356237309515f;
    }
    __syncthreads();
#pragma unroll
    for (int mt = 0; mt < 4; ++mt)
      dmreg[mt] = *(const f32x4*)(demf + mt * 16 + lhi4 * 4);
    // reads complete before this thread hits the kb-loop barrier; writes to
    // lds_x only happen after all threads pass that barrier -> safe reuse.
  }

  const unsigned short* abase = Wt + (size_t)cb * 16 * 18432;
  const unsigned short* xbase = Xp + (size_t)n * 2230272;
  int xoffg[11];
#pragma unroll
  for (int j = 0; j < 11; ++j) {
    int c = j * 256 + t;
    int r = c / 264, rc = c - r * 264;
    int off = (r0 + r) * 33792 + rc * 8;
    if (c >= 2640) off = 0;
    xoffg[j] = off;
  }

  f32x4 acc[4][8];
#pragma unroll
  for (int a = 0; a < 4; ++a)
#pragma unroll
    for (int bq = 0; bq < 8; ++bq) acc[a][bq] = (f32x4){0.f, 0.f, 0.f, 0.f};

  const int aoff = lhi4 * 128 + l15 * 8;
  const int xoffb = lhi4 * 528 + (wv * 16 + l15) * 8;

  for (int kb = 0; kb < 16; ++kb) {
    __syncthreads();
    const char* ab = (const char*)(abase + (size_t)kb * 18432);
#pragma unroll
    for (int i = 0; i < 9; ++i)
      g2l16(ab + i * 4096 + t * 16, (char*)lds_a + i * 4096 + t * 16);
#pragma unroll
    for (int j = 0; j < 11; ++j)
      g2l16(xbase + xoffg[j] + kb * 2112, (char*)lds_x + j * 4096 + t * 16);
    __syncthreads();

#pragma unroll
    for (int dw = 0; dw < 3; ++dw) {
      short8 bf[10];
#pragma unroll
      for (int rr = 0; rr < 10; ++rr)
        bf[rr] = *(const short8*)(lds_x + rr * 2112 + dw * 8 + xoffb);
#pragma unroll
      for (int dh = 0; dh < 3; ++dh) {
#pragma unroll
        for (int mt = 0; mt < 4; ++mt) {
          short8 af = *(const short8*)(lds_a + (dh * 3 + dw) * 2048 + mt * 512 + aoff);
#pragma unroll
          for (int ri = 0; ri < 8; ++ri)
            acc[mt][ri] =
                __builtin_amdgcn_mfma_f32_16x16x32_bf16(af, bf[ri + dh], acc[mt][ri], 0, 0, 0);
        }
      }
    }
  }

  float nw = nw_p[0];
  int col = wv * 16 + l15;
  float nz[8];
#pragma unroll
  for (int ri = 0; ri < 8; ++ri)
    nz[ri] = nw * noise[((size_t)n * 64 + r0 + ri) * 64 + col];
#pragma unroll
  for (int mt = 0; mt < 4; ++mt) {
    f32x4 dm4 = dmreg[mt];
#pragma unroll
    for (int c = 0; c < 4; ++c) {
      int co = cb * 64 + mt * 16 + lhi4 * 4 + c;
      float ab2 = act_bias[co];
      float dm = dm4[c];
#pragma unroll
      for (int ri = 0; ri < 8; ++ri) {
        float v = dm * acc[mt][ri][c] + nz[ri] + ab2;
        v = v > 0.f ? v : 0.2f * v;
        out[(((size_t)n * 512 + co) * 64 + (r0 + ri)) * 64 + col] = v;
      }
    }
  }
}

extern "C" void kernel_launch(void* const* d_in, const int* in_sizes, int n_in,
                              void* d_out, int out_size, void* d_ws, size_t ws_size,
                              hipStream_t stream) {
  const float* x     = (const float*)d_in[0];
  const float* style = (const float*)d_in[1];
  const float* noise = (const float*)d_in[2];
  const float* cw    = (const float*)d_in[3];
  const float* mw    = (const float*)d_in[4];
  const float* mb    = (const float*)d_in[5];
  const float* nw    = (const float*)d_in[6];
  const float* ab    = (const float*)d_in[7];
  float* out = (float*)d_out;

  char* ws = (char*)d_ws;
  float* s_g  = (float*)ws;                              // 16 KB
  float* wsq  = (float*)(ws + 32768);                    // 1 MB
  unsigned short* Wt = (unsigned short*)(ws + 1081344);  // 4,718,592 B
  unsigned short* Xp = (unsigned short*)(ws + 5799936);  // 35,684,352 B (end 41.5 MB)

  k_prep<<<1424, 256, 0, stream>>>(style, mw, mb, cw, x, s_g, wsq, Xp, Wt);
  k_conv<<<dim3(8, 8, 8), 256, 0, stream>>>(Wt, Xp, s_g, wsq, noise, nw, ab, out);
}

// Round 6
// 264.638 us; speedup vs baseline: 1.5574x; 1.1161x over previous
//
#include <hip/hip_runtime.h>
#include <hip/hip_bf16.h>
#include <stdint.h>

// Problem constants: N=8, CIN=512, COUT=512, K=3, H=W=64
// out = demod[n,co]*sqrt2 * conv(cw, s[n,ci]*x) + nw*noise + bias, leaky(0.2)

typedef __attribute__((ext_vector_type(8))) short short8;
typedef __attribute__((ext_vector_type(4))) float f32x4;
typedef __attribute__((ext_vector_type(4))) unsigned int uint4v;
typedef __attribute__((ext_vector_type(2))) unsigned int uint2v;

__device__ __forceinline__ unsigned short f2bf(float f) {
  unsigned u = __builtin_bit_cast(unsigned, f);
  u += 0x7FFFu + ((u >> 16) & 1u);   // round-to-nearest-even
  return (unsigned short)(u >> 16);
}

__device__ __forceinline__ void g2l16(const void* g, void* l) {
  __builtin_amdgcn_global_load_lds(
      (const __attribute__((address_space(1))) void*)g,
      (__attribute__((address_space(3))) void*)l, 16, 0, 0);
}

// ---------------- k_pre: style GEMV (0..1023) | wsq (1024..2047) ----------------
// EXACT R0 code (verified).
__global__ void k_pre(const float* __restrict__ style, const float* __restrict__ mw,
                      const float* __restrict__ mb, const float* __restrict__ cw,
                      float* __restrict__ s_out, float* __restrict__ wsq) {
  int t = threadIdx.x;
  int b = blockIdx.x;
  if (b < 1024) {
    int wid = b * 4 + (t >> 6);   // (n,ci), 4096 total
    int lane = t & 63;
    int n = wid >> 9, ci = wid & 511;
    float sum = 0.f;
#pragma unroll
    for (int i = 0; i < 8; ++i) {
      int k = lane + i * 64;
      sum += style[n * 512 + k] * mw[ci * 512 + k];
    }
#pragma unroll
    for (int off = 32; off; off >>= 1) sum += __shfl_xor(sum, off, 64);
    if (lane == 0) s_out[wid] = sum + mb[ci];
  } else {
    int id = (b - 1024) * 256 + t;   // (co,ci), 262144 total
    const float* p = cw + (size_t)id * 9;
    float a = 0.f;
#pragma unroll
    for (int j = 0; j < 9; ++j) a += p[j] * p[j];
    wsq[id] = a;
  }
}

// ---------------- k_mid: xpad(0..511) | demod(512..1535) | Wt(1536..1791) | halo --
// xpad/demod/halo byte-identical to R0 (verified). Wt role rebuilt for 32-co tiles:
// Wt layout: [cb 16][kb 16]{ [tap 9][mt 2][lhi 4][m 16][8ci] } bf16, tile 18432 B.
// Xp layout: [n 8][row 66][kb 16][lhi 4][col 66][8] bf16.
__global__ void k_mid(const float* __restrict__ s, const float* __restrict__ wsq,
                      const float* __restrict__ x, const float* __restrict__ cw,
                      float* __restrict__ demod, unsigned short* __restrict__ Xp,
                      unsigned short* __restrict__ Wt) {
  __shared__ char smem[74240];
  int t = threadIdx.x;
  int b = blockIdx.x;
  if (b < 512) {
    // ---- xpad: block (n,h): all 512 ci, 64 cols. float4 loads, bf16 LDS tile ----
    int n = b >> 6, h = b & 63;
    short* ldsx = (short*)smem;              // [ci 512][68]  69632 B
    float* sxf = (float*)(smem + 69632);     // [512]
    sxf[t] = s[n * 512 + t];
    sxf[t + 256] = s[n * 512 + 256 + t];
    __syncthreads();
    const float* xb = x + ((size_t)n * 512) * 4096 + h * 64;
#pragma unroll
    for (int i = 0; i < 32; ++i) {
      int L = t + i * 256;
      int ci = L >> 4, q = L & 15;
      f32x4 v = *(const f32x4*)(xb + (size_t)ci * 4096 + q * 4);
      float sv = sxf[ci];
      uint2v o;
      o.x = f2bf(v.x * sv) | ((unsigned)f2bf(v.y * sv) << 16);
      o.y = f2bf(v.z * sv) | ((unsigned)f2bf(v.w * sv) << 16);
      *(uint2v*)(ldsx + ci * 68 + q * 4) = o;
    }
    __syncthreads();
    unsigned short* nb = Xp + (size_t)n * 2230272 + (size_t)(h + 1) * 33792;
#pragma unroll
    for (int r = 0; r < 16; ++r) {
      int u = t + r * 256;
      int cig = u >> 6, col = u & 63;   // cig = kb*4+lhi (ci = cig*8+j)
      unsigned v[8];
#pragma unroll
      for (int j = 0; j < 8; ++j)
        v[j] = (unsigned short)ldsx[(cig * 8 + j) * 68 + col];
      uint4v o;
      o.x = v[0] | (v[1] << 16);
      o.y = v[2] | (v[3] << 16);
      o.z = v[4] | (v[5] << 16);
      o.w = v[6] | (v[7] << 16);
      *(uint4v*)(nb + ((size_t)cig * 66 + col + 1) * 8) = o;
    }
  } else if (b < 1536) {
    // ---- demod ----
    int wid = (b - 512) * 4 + (t >> 6);   // (n,co)
    int lane = t & 63;
    int n = wid >> 9, co = wid & 511;
    float sum = 0.f;
#pragma unroll
    for (int i = 0; i < 8; ++i) {
      int ci = lane + i * 64;
      float sv = s[n * 512 + ci];
      sum += sv * sv * wsq[co * 512 + ci];
    }
#pragma unroll
    for (int off = 32; off; off >>= 1) sum += __shfl_xor(sum, off, 64);
    if (lane == 0) demod[wid] = rsqrtf(sum + 1e-8f) * 1.41421356237309515f;
  } else if (b < 1792) {
    // ---- Wt build: one block per (cb32,kb); LDS [32][289] floats, conflict-free --
    int bb = b - 1536;
    int cb = bb >> 4, kb = bb & 15;      // cb 0..15 (32-co tiles)
    float* ldsf = (float*)smem;          // [32][289]  36992 B
#pragma unroll
    for (int i = 0; i < 36; ++i) {
      int idx = t + i * 256;             // 0..9215
      int seg = idx / 288, off = idx - seg * 288;
      ldsf[seg * 289 + off] = cw[(size_t)(cb * 32 + seg) * 4608 + kb * 288 + off];
    }
    __syncthreads();
    unsigned short* ob = Wt + (size_t)(cb * 16 + kb) * 9216;
#pragma unroll
    for (int i = 0; i < 5; ++i) {
      int c = t + i * 256;               // chunk 0..1151
      if (c < 1152) {
        int m = c & 15, lhi = (c >> 4) & 3, mt = (c >> 6) & 1, tap = c >> 7;
        int co_rel = mt * 16 + m;
        unsigned v[8];
#pragma unroll
        for (int j = 0; j < 8; ++j)
          v[j] = f2bf(ldsf[co_rel * 289 + (lhi * 8 + j) * 9 + tap]);
        uint4v o;
        o.x = v[0] | (v[1] << 16);
        o.y = v[2] | (v[3] << 16);
        o.z = v[4] | (v[5] << 16);
        o.w = v[6] | (v[7] << 16);
        *(uint4v*)(ob + (size_t)c * 8) = o;
      }
    }
  } else {
    // ---- halo zero: 16640 16B-chunks per n; 17 parts x 1024 chunks ----
    int bb = b - 1792;
    int n = bb / 17, part = bb % 17;
    uint4v z = (uint4v){0u, 0u, 0u, 0u};
    unsigned short* base = Xp + (size_t)n * 2230272;
#pragma unroll
    for (int i = 0; i < 4; ++i) {
      int id = part * 1024 + i * 256 + t;
      if (id < 16640) {
        size_t off;
        if (id < 8448) {                 // rows 0 and 65, full rows
          int row = (id < 4224) ? 0 : 65;
          int c = id - ((id < 4224) ? 0 : 4224);
          off = (size_t)row * 33792 + (size_t)c * 8;
        } else {                         // cols 0 and 65, rows 1..64
          int id2 = id - 8448;
          int row = 1 + (id2 >> 7);
          int rem = id2 & 127;
          int klhi = rem >> 1;
          int col = (rem & 1) ? 65 : 0;
          off = (size_t)row * 33792 + ((size_t)klhi * 66 + col) * 8;
        }
        *(uint4v*)(base + off) = z;
      }
    }
  }
}

// ---------------- k_conv: 32co x 4row tiles -> 47 KB LDS -> 3 blocks/CU ----------
// Same verified schedule (2-barrier kb loop, g2l16 staging, identical fragment
// layouts); only tile shape changed to raise occupancy 2->3 blocks/CU.
__global__ void __launch_bounds__(256, 3) k_conv(
    const unsigned short* __restrict__ Wt, const unsigned short* __restrict__ Xp,
    const float* __restrict__ demod, const float* __restrict__ noise,
    const float* __restrict__ nw_p, const float* __restrict__ act_bias,
    float* __restrict__ out) {
  __shared__ short lds_a[9216];    // 18432 B
  __shared__ short lds_x[14336];   // 28672 B (25344 used + staging slack)
  int t = threadIdx.x;
  int r0 = blockIdx.x * 4;         // 16 rx tiles of 4 rows
  int cb = blockIdx.y;             // 16 co tiles of 32
  int n = blockIdx.z;
  int lane = t & 63, wv = t >> 6;
  int l15 = lane & 15, lhi4 = lane >> 4;

  const unsigned short* abase = Wt + (size_t)cb * 16 * 9216;
  const unsigned short* xbase = Xp + (size_t)n * 2230272;
  int xoffg[7];
#pragma unroll
  for (int j = 0; j < 7; ++j) {
    int c = j * 256 + t;           // 6 rows x 264 chunks = 1584
    int r = c / 264, rc = c - r * 264;
    int off = (r0 + r) * 33792 + rc * 8;
    if (c >= 1584) off = 0;
    xoffg[j] = off;
  }

  f32x4 acc[2][4];
#pragma unroll
  for (int a = 0; a < 2; ++a)
#pragma unroll
    for (int bq = 0; bq < 4; ++bq) acc[a][bq] = (f32x4){0.f, 0.f, 0.f, 0.f};

  const int aoff = lhi4 * 128 + l15 * 8;
  const int xoffb = lhi4 * 528 + (wv * 16 + l15) * 8;

  for (int kb = 0; kb < 16; ++kb) {
    __syncthreads();
    const char* ab = (const char*)(abase + (size_t)kb * 9216);
#pragma unroll
    for (int i = 0; i < 5; ++i) {
      int c = i * 256 + t;         // 1152 chunks of 16B
      if (c < 1152) g2l16(ab + c * 16, (char*)lds_a + c * 16);
    }
#pragma unroll
    for (int j = 0; j < 7; ++j)
      g2l16(xbase + xoffg[j] + kb * 2112, (char*)lds_x + j * 4096 + t * 16);
    __syncthreads();

#pragma unroll
    for (int dw = 0; dw < 3; ++dw) {
      short8 bf[6];
#pragma unroll
      for (int rr = 0; rr < 6; ++rr)
        bf[rr] = *(const short8*)(lds_x + rr * 2112 + dw * 8 + xoffb);
#pragma unroll
      for (int dh = 0; dh < 3; ++dh) {
#pragma unroll
        for (int mt = 0; mt < 2; ++mt) {
          short8 af = *(const short8*)(lds_a + (dh * 3 + dw) * 1024 + mt * 512 + aoff);
#pragma unroll
          for (int ri = 0; ri < 4; ++ri)
            acc[mt][ri] =
                __builtin_amdgcn_mfma_f32_16x16x32_bf16(af, bf[ri + dh], acc[mt][ri], 0, 0, 0);
        }
      }
    }
  }

  float nw = nw_p[0];
  int col = wv * 16 + l15;
  float nz[4];
#pragma unroll
  for (int ri = 0; ri < 4; ++ri)
    nz[ri] = nw * noise[((size_t)n * 64 + r0 + ri) * 64 + col];
#pragma unroll
  for (int mt = 0; mt < 2; ++mt) {
    f32x4 dm4 = *(const f32x4*)(demod + n * 512 + cb * 32 + mt * 16 + lhi4 * 4);
#pragma unroll
    for (int c = 0; c < 4; ++c) {
      int co = cb * 32 + mt * 16 + lhi4 * 4 + c;
      float ab2 = act_bias[co];
      float dm = dm4[c];
#pragma unroll
      for (int ri = 0; ri < 4; ++ri) {
        float v = dm * acc[mt][ri][c] + nz[ri] + ab2;
        v = v > 0.f ? v : 0.2f * v;
        out[(((size_t)n * 512 + co) * 64 + (r0 + ri)) * 64 + col] = v;
      }
    }
  }
}

extern "C" void kernel_launch(void* const* d_in, const int* in_sizes, int n_in,
                              void* d_out, int out_size, void* d_ws, size_t ws_size,
                              hipStream_t stream) {
  const float* x     = (const float*)d_in[0];
  const float* style = (const float*)d_in[1];
  const float* noise = (const float*)d_in[2];
  const float* cw    = (const float*)d_in[3];
  const float* mw    = (const float*)d_in[4];
  const float* mb    = (const float*)d_in[5];
  const float* nw    = (const float*)d_in[6];
  const float* ab    = (const float*)d_in[7];
  float* out = (float*)d_out;

  char* ws = (char*)d_ws;
  float* s_buf  = (float*)ws;                            // 16 KB
  float* demod  = (float*)(ws + 16384);                  // 16 KB
  float* wsq    = (float*)(ws + 32768);                  // 1 MB
  unsigned short* Wt = (unsigned short*)(ws + 1081344);  // 4,718,592 B
  unsigned short* Xp = (unsigned short*)(ws + 5799936);  // 35,684,352 B (end 41.5 MB)

  k_pre<<<2048, 256, 0, stream>>>(style, mw, mb, cw, s_buf, wsq);
  k_mid<<<1928, 256, 0, stream>>>(s_buf, wsq, x, cw, demod, Xp, Wt);
  k_conv<<<dim3(16, 16, 8), 256, 0, stream>>>(Wt, Xp, demod, noise, nw, ab, out);
}